// Round 4
// baseline (247.064 us; speedup 1.0000x reference)
//
#include <hip/hip_runtime.h>

typedef __attribute__((ext_vector_type(8))) short short8;
typedef __attribute__((ext_vector_type(4))) short short4_t;
typedef __attribute__((ext_vector_type(8))) __bf16 bf16x8;
typedef __attribute__((ext_vector_type(4))) float floatx4;

union S8B8 { short8 s; bf16x8 b; };

__device__ __forceinline__ short f2bf(float f) {
    union { float f; unsigned u; } v; v.f = f;
    unsigned r = v.u + 0x7fffu + ((v.u >> 16) & 1u);   // RNE
    return (short)(r >> 16);
}
__device__ __forceinline__ float bf2f(short s) {
    union { unsigned u; float f; } v; v.u = ((unsigned)(unsigned short)s) << 16;
    return v.f;
}
__device__ __forceinline__ float bflo(unsigned u) { return __uint_as_float(u << 16); }
__device__ __forceinline__ float bfhi(unsigned u) { return __uint_as_float(u & 0xffff0000u); }

// ================ k_A: hpb | coalesced packs | refined init | zeros (R3 verbatim) ================
__global__ __launch_bounds__(256) void k_A(const float* __restrict__ W1, const float* __restrict__ W2,
                                           const float* __restrict__ Wc1, const float* __restrict__ proto,
                                           const float* __restrict__ bc1,
                                           short* __restrict__ W1p, short* __restrict__ W2p,
                                           short* __restrict__ wqp, float* __restrict__ refined,
                                           float* __restrict__ wmean, float* __restrict__ hpb,
                                           int* __restrict__ bar, float* __restrict__ wsum,
                                           float* __restrict__ dout) {
    int tid = threadIdx.x, bid = blockIdx.x;
    if (bid < 32) {
        int r = bid;
        const float* pr = proto + r * 512;
        const float* wc = Wc1 + tid;
        float a0 = 0.f, a1 = 0.f, a2 = 0.f, a3 = 0.f;
#pragma unroll 4
        for (int i = 0; i < 512; i += 4) {
            float4 p4 = *(const float4*)&pr[i];
            float w0 = wc[(size_t)i * 256];
            float w1 = wc[(size_t)(i + 1) * 256];
            float w2 = wc[(size_t)(i + 2) * 256];
            float w3 = wc[(size_t)(i + 3) * 256];
            a0 += p4.x * w0;
            a1 += p4.y * w1;
            a2 += p4.z * w2;
            a3 += p4.w * w3;
        }
        hpb[r * 256 + tid] = bc1[tid] + ((a0 + a1) + (a2 + a3));
        return;
    }
    if (bid < 480) {
        int idx = (bid - 32) * 256 + tid;   // < 114688
        if (idx < 65536) {                  // W1 pack
            int kg = idx >> 9, n = idx & 511;
            short8 o;
#pragma unroll
            for (int j = 0; j < 8; j++) o[j] = f2bf(W1[(size_t)(kg * 8 + j) * 512 + n]);
            *(short8*)&W1p[((size_t)kg * 512 + n) * 8] = o;
        } else if (idx < 98304) {           // W2 pack
            int j2 = idx - 65536;
            int kg = j2 >> 9, n = j2 & 511;
            short8 o;
#pragma unroll
            for (int j = 0; j < 8; j++) o[j] = f2bf(W2[(size_t)(kg * 8 + j) * 512 + n]);
            *(short8*)&W2p[((size_t)kg * 512 + n) * 8] = o;
        } else {                            // Wc1[512:] pack
            int j3 = idx - 98304;
            int kg = j3 >> 8, n = j3 & 255;
            short8 o;
#pragma unroll
            for (int j = 0; j < 8; j++) o[j] = f2bf(Wc1[(size_t)(512 + kg * 8 + j) * 256 + n]);
            *(short8*)&wqp[((size_t)kg * 256 + n) * 8] = o;
        }
        return;
    }
    if (bid < 544) {
        int idx = (bid - 480) * 256 + tid;  // < 16384
        refined[idx] = proto[idx];
        return;
    }
    if (bid < 736) {
        int idx = (bid - 544) * 256 + tid;  // < 49152
        wmean[idx] = 0.f;
        return;
    }
    {
        if (tid < 96) wsum[tid] = 0.f;
        else if (tid < 104) bar[tid - 96] = 0;
        else if (tid >= 128 && tid < 160) dout[16384 + tid - 128] = 0.f;
    }
}

// ================ global spin barrier (16 co-resident blocks — PROVEN size, do not widen) ================
__device__ __forceinline__ void gbar(int* bar, int phase, int nblk) {
    __syncthreads();
    if (threadIdx.x == 0) {
        __threadfence();
        __hip_atomic_fetch_add(&bar[phase], 1, __ATOMIC_ACQ_REL, __HIP_MEMORY_SCOPE_AGENT);
        while (__hip_atomic_load(&bar[phase], __ATOMIC_ACQUIRE, __HIP_MEMORY_SCOPE_AGENT) < nblk)
            __builtin_amdgcn_s_sleep(1);
    }
    __syncthreads();
}

// ================ k_M: 0..255 wmean producers | 256..1279 confidence | 1280..1295 MLP (waits) ================
__global__ __launch_bounds__(256) void k_M(const float* __restrict__ qd, const float* __restrict__ qf,
                                           float* __restrict__ wmean, float* __restrict__ wsum,
                                           const short* __restrict__ W1p, const float* __restrict__ b1,
                                           const short* __restrict__ W2p, const float* __restrict__ b2,
                                           float* __restrict__ refined, short* __restrict__ hb,
                                           int* __restrict__ bar,
                                           const short* __restrict__ wqp, const float* __restrict__ hpb,
                                           const float* __restrict__ Wc2, const float* __restrict__ bc2p,
                                           float* __restrict__ dout) {
    __shared__ float smem[12672];   // 50,688 B — P: soft_lds[96][264]s; C: R3 layout; M: red[4][32][36]
    int tid = threadIdx.x, lane = tid & 63, w = tid >> 6;
    int ml = lane & 15, q8 = lane >> 4;
    int bid = blockIdx.x;

    if (bid < 256) {
        // ---- P: wmean producer with in-block softmax; B-frags direct from qf (no B_lds, no step syncs) ----
        short* soft_lds = (short*)smem;    // [96][264]
        int kc = bid >> 2, ns = bid & 3;
        int qb0 = kc * 256, c0 = ns * 128;
        {
            float d[32];
            const float4* p = (const float4*)(qd + (size_t)(qb0 + tid) * 32);
#pragma unroll
            for (int j = 0; j < 8; j++) {
                float4 v = p[j];
                d[4 * j] = v.x; d[4 * j + 1] = v.y; d[4 * j + 2] = v.z; d[4 * j + 3] = v.w;
            }
#pragma unroll
            for (int s = 0; s < 3; s++) {
                float inv = -1.0f / (float)(s + 1);
                float e[32];
                float sum = 0.f;
#pragma unroll
                for (int k = 0; k < 32; k++) { e[k] = __expf(d[k] * inv); sum += e[k]; }
                float r = 1.0f / sum;
#pragma unroll
                for (int k = 0; k < 32; k++)
                    soft_lds[(s * 32 + k) * 264 + tid] = f2bf(e[k] * r);
            }
        }
        __syncthreads();

        if (ns == 0 && tid < 96) {
            const short* row = &soft_lds[tid * 264];
            float ssum = 0.f;
#pragma unroll 4
            for (int j = 0; j < 32; j++) {
                short8 v = *(const short8*)&row[j * 8];
#pragma unroll
                for (int i = 0; i < 8; i++) ssum += bf2f(v[i]);
            }
            atomicAdd(&wsum[tid], ssum);
        }

        floatx4 acc[6][2];
#pragma unroll
        for (int mt = 0; mt < 6; mt++)
#pragma unroll
            for (int nt = 0; nt < 2; nt++) acc[mt][nt] = (floatx4){0.f, 0.f, 0.f, 0.f};

        for (int step = 0; step < 8; step++) {
            int qb = step * 32;
            S8B8 a[6];
#pragma unroll
            for (int mt = 0; mt < 6; mt++)
                a[mt].s = *(const short8*)&soft_lds[(mt * 16 + ml) * 264 + qb + q8 * 8];
            S8B8 bfr[2];
#pragma unroll
            for (int nt = 0; nt < 2; nt++) {
                int c = c0 + w * 32 + nt * 16 + ml;
                const float* qp = &qf[(size_t)(qb0 + qb + q8 * 8) * 512 + c];
                short8 t;
#pragma unroll
                for (int i = 0; i < 8; i++) t[i] = f2bf(qp[(size_t)i * 512]);
                bfr[nt].s = t;
            }
#pragma unroll
            for (int nt = 0; nt < 2; nt++)
#pragma unroll
                for (int mt = 0; mt < 6; mt++)
                    acc[mt][nt] = __builtin_amdgcn_mfma_f32_16x16x32_bf16(a[mt].b, bfr[nt].b, acc[mt][nt], 0, 0, 0);
        }
#pragma unroll
        for (int mt = 0; mt < 6; mt++) {
#pragma unroll
            for (int nt = 0; nt < 2; nt++) {
                int c = c0 + w * 32 + nt * 16 + ml;
#pragma unroll
                for (int r = 0; r < 4; r++) {
                    int m = mt * 16 + q8 * 4 + r;
                    atomicAdd(&wmean[(size_t)m * 512 + c], acc[mt][nt][r]);
                }
            }
        }
        // signal producer-done
        __syncthreads();
        if (tid == 0) {
            __threadfence();
            __hip_atomic_fetch_add(&bar[6], 1, __ATOMIC_ACQ_REL, __HIP_MEMORY_SCOPE_AGENT);
        }
        return;
    }

    if (bid < 1280) {
        // ---- C: confidence, independent of P (needs only k_A outputs + qf) ----
        short* hq_lds = (short*)smem;                  // [16][280] s
        short* hp_s   = (short*)smem + 4480;           // [32][260] s
        float* wc2s   = smem + 6400;                   // 256 f
        float* confl  = smem + 6656;                   // 32 f
        int q0 = (bid - 256) * 16;

        wc2s[tid] = Wc2[tid];
        if (tid < 32) confl[tid] = 0.f;
#pragma unroll
        for (int i = 0; i < 8; i++) {                  // hp: 2048 float4 -> bf16 short4
            int idx = i * 256 + tid;
            int r = idx >> 6, c = (idx & 63) * 4;
            float4 v = *(const float4*)&hpb[r * 256 + c];
            short4_t o;
            o[0] = f2bf(v.x); o[1] = f2bf(v.y); o[2] = f2bf(v.z); o[3] = f2bf(v.w);
            *(short4_t*)&hp_s[r * 260 + c] = o;
        }
        {   // hq tile: [16 q][256 h] = qf[q0..q0+16] @ wqp, K=512
            floatx4 acc[4];
#pragma unroll
            for (int nt = 0; nt < 4; nt++) acc[nt] = (floatx4){0.f, 0.f, 0.f, 0.f};
            const float* qfa = qf + (size_t)(q0 + ml) * 512 + q8 * 8;
#pragma unroll 4
            for (int kc = 0; kc < 512; kc += 32) {
                float4 fa = *(const float4*)&qfa[kc];
                float4 fb = *(const float4*)&qfa[kc + 4];
                short8 t;
                t[0] = f2bf(fa.x); t[1] = f2bf(fa.y); t[2] = f2bf(fa.z); t[3] = f2bf(fa.w);
                t[4] = f2bf(fb.x); t[5] = f2bf(fb.y); t[6] = f2bf(fb.z); t[7] = f2bf(fb.w);
                S8B8 a; a.s = t;
#pragma unroll
                for (int nt = 0; nt < 4; nt++) {
                    int col = w * 64 + nt * 16 + ml;
                    S8B8 b; b.s = *(const short8*)&wqp[((size_t)((kc >> 3) + q8) * 256 + col) * 8];
                    acc[nt] = __builtin_amdgcn_mfma_f32_16x16x32_bf16(a.b, b.b, acc[nt], 0, 0, 0);
                }
            }
#pragma unroll
            for (int nt = 0; nt < 4; nt++)
#pragma unroll
                for (int r = 0; r < 4; r++)
                    hq_lds[(q8 * 4 + r) * 280 + w * 64 + nt * 16 + ml] = f2bf(acc[nt][r]);
        }
        __syncthreads();

        int q = tid & 15, kg = tid >> 4;
        int k0 = kg, k1 = kg + 16;
        float s0 = 0.f, s1 = 0.f;
        for (int h = 0; h < 256; h += 4) {
            uint2 hv = *(uint2*)&hq_lds[q * 280 + h];
            float f0 = bflo(hv.x), f1 = bfhi(hv.x), f2 = bflo(hv.y), f3 = bfhi(hv.y);
            uint2 u0 = *(uint2*)&hp_s[k0 * 260 + h];
            uint2 u1 = *(uint2*)&hp_s[k1 * 260 + h];
            float4 wv = *(float4*)&wc2s[h];
            s0 += fmaxf(bflo(u0.x) + f0, 0.f) * wv.x;
            s0 += fmaxf(bfhi(u0.x) + f1, 0.f) * wv.y;
            s0 += fmaxf(bflo(u0.y) + f2, 0.f) * wv.z;
            s0 += fmaxf(bfhi(u0.y) + f3, 0.f) * wv.w;
            s1 += fmaxf(bflo(u1.x) + f0, 0.f) * wv.x;
            s1 += fmaxf(bfhi(u1.x) + f1, 0.f) * wv.y;
            s1 += fmaxf(bflo(u1.y) + f2, 0.f) * wv.z;
            s1 += fmaxf(bfhi(u1.y) + f3, 0.f) * wv.w;
        }
        float bc2 = bc2p[0];
        float v0 = 1.f / (1.f + __expf(-(s0 + bc2)));
        float v1 = 1.f / (1.f + __expf(-(s1 + bc2)));
        atomicAdd(&confl[k0], v0);
        atomicAdd(&confl[k1], v1);
        __syncthreads();
        if (tid < 32) atomicAdd(&dout[16384 + tid], confl[tid] * (1.0f / 16384.0f));
        return;
    }

    // ---- M: 16 MLP blocks — wait for all 256 producers, then R0-proven structure ----
    if (tid == 0) {
        while (__hip_atomic_load(&bar[6], __ATOMIC_ACQUIRE, __HIP_MEMORY_SCOPE_AGENT) < 256)
            __builtin_amdgcn_s_sleep(1);
    }
    __syncthreads();
    {
        float (*red)[32][36] = (float(*)[32][36])smem;   // 4608 f
        int nb = bid - 1280;
        int phase = 0;
        for (int s = 0; s < 3; s++) {
            {   // layer 1: hb[:, 32-col slice] = relu(concat @ W1 + b1) bf16
                const float* srcA = (w < 2) ? refined : (wmean + (size_t)s * 32 * 512 - 512);
                float iv0 = 1.f, iv1 = 1.f;
                if (w >= 2) {
                    iv0 = 1.f / fmaxf(wsum[s * 32 + ml], 1e-6f);
                    iv1 = 1.f / fmaxf(wsum[s * 32 + 16 + ml], 1e-6f);
                }
                int kw = w * 256;
                floatx4 acc[2][2];
#pragma unroll
                for (int mt = 0; mt < 2; mt++)
#pragma unroll
                    for (int nt = 0; nt < 2; nt++) acc[mt][nt] = (floatx4){0.f, 0.f, 0.f, 0.f};
                for (int st = 0; st < 8; st++) {
                    int k0 = kw + st * 32 + q8 * 8;
                    S8B8 a[2];
#pragma unroll
                    for (int mt = 0; mt < 2; mt++) {
                        float sc = mt ? iv1 : iv0;
                        const float* p = &srcA[(size_t)(mt * 16 + ml) * 512 + k0];
                        float4 f0 = *(const float4*)p;
                        float4 f1 = *(const float4*)(p + 4);
                        short8 t;
                        t[0] = f2bf(f0.x * sc); t[1] = f2bf(f0.y * sc);
                        t[2] = f2bf(f0.z * sc); t[3] = f2bf(f0.w * sc);
                        t[4] = f2bf(f1.x * sc); t[5] = f2bf(f1.y * sc);
                        t[6] = f2bf(f1.z * sc); t[7] = f2bf(f1.w * sc);
                        a[mt].s = t;
                    }
#pragma unroll
                    for (int nt = 0; nt < 2; nt++) {
                        int n = nb * 32 + nt * 16 + ml;
                        S8B8 b; b.s = *(const short8*)&W1p[((size_t)(k0 >> 3) * 512 + n) * 8];
#pragma unroll
                        for (int mt = 0; mt < 2; mt++)
                            acc[mt][nt] = __builtin_amdgcn_mfma_f32_16x16x32_bf16(a[mt].b, b.b, acc[mt][nt], 0, 0, 0);
                    }
                }
                __syncthreads();
#pragma unroll
                for (int mt = 0; mt < 2; mt++)
#pragma unroll
                    for (int nt = 0; nt < 2; nt++)
#pragma unroll
                        for (int r = 0; r < 4; r++)
                            red[w][mt * 16 + q8 * 4 + r][nt * 16 + ml] = acc[mt][nt][r];
                __syncthreads();
                int m = tid >> 3, n0 = (tid & 7) * 4;
                short4_t o;
#pragma unroll
                for (int i = 0; i < 4; i++) {
                    float v = b1[nb * 32 + n0 + i];
#pragma unroll
                    for (int w4 = 0; w4 < 4; w4++) v += red[w4][m][n0 + i];
                    o[i] = f2bf(fmaxf(v, 0.f));
                }
                *(short4_t*)&hb[(size_t)m * 512 + nb * 32 + n0] = o;
            }
            gbar(bar, phase++, 16);
            {   // layer 2: refined[:, slice] += 0.1*(hb @ W2 + b2)
                int kw = w * 128;
                floatx4 acc[2][2];
#pragma unroll
                for (int mt = 0; mt < 2; mt++)
#pragma unroll
                    for (int nt = 0; nt < 2; nt++) acc[mt][nt] = (floatx4){0.f, 0.f, 0.f, 0.f};
                for (int st = 0; st < 4; st++) {
                    int k0 = kw + st * 32 + q8 * 8;
                    S8B8 a[2];
#pragma unroll
                    for (int mt = 0; mt < 2; mt++)
                        a[mt].s = *(const short8*)&hb[(size_t)(mt * 16 + ml) * 512 + k0];
#pragma unroll
                    for (int nt = 0; nt < 2; nt++) {
                        int n = nb * 32 + nt * 16 + ml;
                        S8B8 b; b.s = *(const short8*)&W2p[((size_t)(k0 >> 3) * 512 + n) * 8];
#pragma unroll
                        for (int mt = 0; mt < 2; mt++)
                            acc[mt][nt] = __builtin_amdgcn_mfma_f32_16x16x32_bf16(a[mt].b, b.b, acc[mt][nt], 0, 0, 0);
                    }
                }
                __syncthreads();
#pragma unroll
                for (int mt = 0; mt < 2; mt++)
#pragma unroll
                    for (int nt = 0; nt < 2; nt++)
#pragma unroll
                        for (int r = 0; r < 4; r++)
                            red[w][mt * 16 + q8 * 4 + r][nt * 16 + ml] = acc[mt][nt][r];
                __syncthreads();
                int m = tid >> 3, n0 = (tid & 7) * 4;
#pragma unroll
                for (int i = 0; i < 4; i++) {
                    int c = nb * 32 + n0 + i;
                    float v = b2[c];
#pragma unroll
                    for (int w4 = 0; w4 < 4; w4++) v += red[w4][m][n0 + i];
                    float val = refined[(size_t)m * 512 + c] + 0.1f * v;
                    refined[(size_t)m * 512 + c] = val;
                    if (s == 2) dout[(size_t)m * 512 + c] = val;
                }
            }
            if (s < 2) gbar(bar, phase++, 16);
        }
    }
}

extern "C" void kernel_launch(void* const* d_in, const int* in_sizes, int n_in,
                              void* d_out, int out_size, void* d_ws, size_t ws_size,
                              hipStream_t stream) {
    const float* proto = (const float*)d_in[0];
    const float* qf    = (const float*)d_in[1];
    const float* qd    = (const float*)d_in[2];
    const float* W1    = (const float*)d_in[3];
    const float* b1    = (const float*)d_in[4];
    const float* W2    = (const float*)d_in[5];
    const float* b2    = (const float*)d_in[6];
    const float* Wc1   = (const float*)d_in[7];
    const float* bc1   = (const float*)d_in[8];
    const float* Wc2   = (const float*)d_in[9];
    const float* bc2   = (const float*)d_in[10];
    float* out = (float*)d_out;

    float* ws = (float*)d_ws;
    float* wmean   = ws;                         // 49,152 f (raw accumulator)
    float* refined = ws + 49152;                 // 16,384 f
    short* hb      = (short*)(ws + 65536);       // 16,384 s
    short* W1p     = (short*)(ws + 73728);       // 524,288 s
    short* W2p     = (short*)(ws + 335872);      // 262,144 s
    short* wqp     = (short*)(ws + 466944);      // 131,072 s
    float* hpb     = ws + 532480;                // 8,192 f
    int*   bar     = (int*)(ws + 540672);        // 8 ints
    float* wsum    = ws + 540680;                // 96 f

    k_A<<<737, 256, 0, stream>>>(W1, W2, Wc1, proto, bc1, W1p, W2p, wqp,
                                 refined, wmean, hpb, bar, wsum, out);
    k_M<<<1296, 256, 0, stream>>>(qd, qf, wmean, wsum, W1p, b1, W2p, b2, refined, hb, bar,
                                  wqp, hpb, Wc2, bc2, out);
}

// Round 5
// 200.678 us; speedup vs baseline: 1.2311x; 1.2311x over previous
//
#include <hip/hip_runtime.h>

#define NQg 16384

typedef __attribute__((ext_vector_type(8))) short short8;
typedef __attribute__((ext_vector_type(4))) short short4_t;
typedef __attribute__((ext_vector_type(8))) __bf16 bf16x8;
typedef __attribute__((ext_vector_type(4))) float floatx4;

union S8B8 { short8 s; bf16x8 b; };

__device__ __forceinline__ short f2bf(float f) {
    union { float f; unsigned u; } v; v.f = f;
    unsigned r = v.u + 0x7fffu + ((v.u >> 16) & 1u);   // RNE
    return (short)(r >> 16);
}
__device__ __forceinline__ float bf2f(short s) {
    union { unsigned u; float f; } v; v.u = ((unsigned)(unsigned short)s) << 16;
    return v.f;
}
__device__ __forceinline__ float bflo(unsigned u) { return __uint_as_float(u << 16); }
__device__ __forceinline__ float bfhi(unsigned u) { return __uint_as_float(u & 0xffff0000u); }

// ================ k_A: softmax->softT | coalesced packs | inits | qf2b cast | hpb ================
__global__ __launch_bounds__(256) void k_A(const float* __restrict__ qd,
                                           const float* __restrict__ W1, const float* __restrict__ W2,
                                           const float* __restrict__ Wc1, const float* __restrict__ proto,
                                           const float* __restrict__ qf, const float* __restrict__ bc1,
                                           short* __restrict__ softT,
                                           short* __restrict__ W1p, short* __restrict__ W2p,
                                           short* __restrict__ wqp, float* __restrict__ refined,
                                           short* __restrict__ qf2b, float* __restrict__ wmean,
                                           float* __restrict__ hpb,
                                           int* __restrict__ bar, float* __restrict__ dout) {
    int tid = threadIdx.x, bid = blockIdx.x;
    if (bid < 64) {
        // softmax -> softT (R0 verbatim)
        int q = bid * 256 + tid;
        float d[32];
        const float4* p = (const float4*)(qd + (size_t)q * 32);
#pragma unroll
        for (int j = 0; j < 8; j++) {
            float4 v = p[j];
            d[4 * j] = v.x; d[4 * j + 1] = v.y; d[4 * j + 2] = v.z; d[4 * j + 3] = v.w;
        }
#pragma unroll
        for (int s = 0; s < 3; s++) {
            float inv = -1.0f / (float)(s + 1);
            float e[32];
            float sum = 0.f;
#pragma unroll
            for (int k = 0; k < 32; k++) { e[k] = __expf(d[k] * inv); sum += e[k]; }
            float r = 1.0f / sum;
#pragma unroll
            for (int k = 0; k < 32; k++)
                softT[(size_t)(s * 32 + k) * NQg + q] = f2bf(e[k] * r);
        }
        return;
    }
    if (bid < 512) {
        // coalesced packs (R3-proven): thread = 8 consecutive k for one n
        int idx = (bid - 64) * 256 + tid;   // < 114688
        if (idx < 65536) {                  // W1 pack
            int kg = idx >> 9, n = idx & 511;
            short8 o;
#pragma unroll
            for (int j = 0; j < 8; j++) o[j] = f2bf(W1[(size_t)(kg * 8 + j) * 512 + n]);
            *(short8*)&W1p[((size_t)kg * 512 + n) * 8] = o;
        } else if (idx < 98304) {           // W2 pack
            int j2 = idx - 65536;
            int kg = j2 >> 9, n = j2 & 511;
            short8 o;
#pragma unroll
            for (int j = 0; j < 8; j++) o[j] = f2bf(W2[(size_t)(kg * 8 + j) * 512 + n]);
            *(short8*)&W2p[((size_t)kg * 512 + n) * 8] = o;
        } else {                            // Wc1[512:] pack
            int j3 = idx - 98304;
            int kg = j3 >> 8, n = j3 & 255;
            short8 o;
#pragma unroll
            for (int j = 0; j < 8; j++) o[j] = f2bf(Wc1[(size_t)(512 + kg * 8 + j) * 256 + n]);
            *(short8*)&wqp[((size_t)kg * 256 + n) * 8] = o;
        }
        return;
    }
    if (bid < 576) {
        int idx = (bid - 512) * 256 + tid;  // < 16384
        refined[idx] = proto[idx];
        return;
    }
    if (bid < 768) {
        int idx = (bid - 576) * 256 + tid;  // < 49152
        wmean[idx] = 0.f;
        return;
    }
    if (bid < 2816) {
        // cast qf -> bf16: 2048 blocks x 4 coalesced float4-groups per thread (R0 proven)
#pragma unroll
        for (int it = 0; it < 4; it++) {
            int j = (bid - 768) * 1024 + it * 256 + tid;   // < 2,097,152
            float4 v = *(const float4*)&qf[(size_t)j * 4];
            short4_t o;
            o[0] = f2bf(v.x); o[1] = f2bf(v.y); o[2] = f2bf(v.z); o[3] = f2bf(v.w);
            *(short4_t*)&qf2b[(size_t)j * 4] = o;
        }
        return;
    }
    if (bid < 2848) {
        // hpb: 4 independent accumulators + unroll (proven)
        int r = bid - 2816;
        const float* pr = proto + r * 512;
        const float* wc = Wc1 + tid;
        float a0 = 0.f, a1 = 0.f, a2 = 0.f, a3 = 0.f;
#pragma unroll 4
        for (int i = 0; i < 512; i += 4) {
            float4 p4 = *(const float4*)&pr[i];
            float w0 = wc[(size_t)i * 256];
            float w1 = wc[(size_t)(i + 1) * 256];
            float w2 = wc[(size_t)(i + 2) * 256];
            float w3 = wc[(size_t)(i + 3) * 256];
            a0 += p4.x * w0;
            a1 += p4.y * w1;
            a2 += p4.z * w2;
            a3 += p4.w * w3;
        }
        hpb[r * 256 + tid] = bc1[tid] + ((a0 + a1) + (a2 + a3));
        return;
    }
    {
        if (tid < 8) bar[tid] = 0;
        else if (tid >= 32 && tid < 64) dout[16384 + tid - 32] = 0.f;
    }
}

// ================ k_B: 0..255 wmean | 256..351 wsuminv | 352..1375 confidence (independent of wmean) ================
__global__ __launch_bounds__(256) void k_B(const short* __restrict__ qf2b,
                                           const short* __restrict__ softT,
                                           float* __restrict__ wmean,
                                           float* __restrict__ wsuminv,
                                           const short* __restrict__ wqp,
                                           const float* __restrict__ hpb,
                                           const float* __restrict__ Wc2,
                                           const float* __restrict__ bc2p,
                                           float* __restrict__ dout) {
    __shared__ float smem[6688];   // 26,752 B — wmean: B_lds(10,240B); wsum: red(1KB); conf: full layout
    int tid = threadIdx.x;
    int lane = tid & 63, w = tid >> 6;
    int ml = lane & 15, q8 = lane >> 4;
    int bid = blockIdx.x;

    if (bid < 256) {
        // ---- wmean (R0-verbatim structure, 44.4us-proven; atomics rotated by kc) ----
        short* B_lds = (short*)smem;       // [128][40]
        int kc = bid >> 2, ns = bid & 3;
        int c0 = ns * 128;
        int qbase0 = kc * 256;
        int c_l = 2 * lane;
        int q_l = 8 * w;

        floatx4 acc[6][2];
#pragma unroll
        for (int mt = 0; mt < 6; mt++)
#pragma unroll
            for (int nt = 0; nt < 2; nt++) acc[mt][nt] = (floatx4){0.f, 0.f, 0.f, 0.f};

        for (int step = 0; step < 8; step++) {
            int qb = qbase0 + step * 32;
            short8 sA, sB;
#pragma unroll
            for (int i = 0; i < 8; i++) {
                unsigned u = *(const unsigned*)&qf2b[(size_t)(qb + q_l + i) * 512 + c0 + c_l];
                sA[i] = (short)(u & 0xffffu);
                sB[i] = (short)(u >> 16);
            }
            __syncthreads();
            *(short8*)&B_lds[c_l * 40 + q_l] = sA;
            *(short8*)&B_lds[(c_l + 1) * 40 + q_l] = sB;
            S8B8 a[6];
#pragma unroll
            for (int mt = 0; mt < 6; mt++)
                a[mt].s = *(const short8*)&softT[(size_t)(mt * 16 + ml) * NQg + qb + q8 * 8];
            __syncthreads();
#pragma unroll
            for (int nt = 0; nt < 2; nt++) {
                S8B8 b; b.s = *(short8*)&B_lds[(w * 32 + nt * 16 + ml) * 40 + q8 * 8];
#pragma unroll
                for (int mt = 0; mt < 6; mt++)
                    acc[mt][nt] = __builtin_amdgcn_mfma_f32_16x16x32_bf16(a[mt].b, b.b, acc[mt][nt], 0, 0, 0);
            }
        }
        int mrot = kc % 6;
#pragma unroll
        for (int mtt = 0; mtt < 6; mtt++) {
            int mt = mtt + mrot; if (mt >= 6) mt -= 6;   // de-burst same-cell atomic storms
#pragma unroll
            for (int nt = 0; nt < 2; nt++) {
                int c = c0 + w * 32 + nt * 16 + ml;
#pragma unroll
                for (int r = 0; r < 4; r++) {
                    int m = mt * 16 + q8 * 4 + r;
                    atomicAdd(&wmean[(size_t)m * 512 + c], acc[mt][nt][r]);
                }
            }
        }
    } else if (bid < 352) {
        // ---- wsuminv (R0 verbatim) ----
        float* red = smem;
        int sk = bid - 256;
        const short* row = softT + (size_t)sk * NQg;
        float s = 0.f;
#pragma unroll
        for (int j = 0; j < 8; j++) {
            short8 v = *(const short8*)&row[j * 2048 + tid * 8];
#pragma unroll
            for (int i = 0; i < 8; i++) s += bf2f(v[i]);
        }
        red[tid] = s;
        __syncthreads();
        for (int off = 128; off > 0; off >>= 1) {
            if (tid < off) red[tid] += red[tid + off];
            __syncthreads();
        }
        if (tid == 0) wsuminv[sk] = 1.0f / fmaxf(red[0], 1e-6f);
    } else {
        // ---- confidence: hq tile in-block from bf16 qf2b (simpler than R3's fp32 path) ----
        short* hq_lds = (short*)smem;                  // [16][280] s
        short* hp_s   = (short*)smem + 4480;           // [32][260] s
        float* wc2s   = smem + 6400;                   // 256 f
        float* confl  = smem + 6656;                   // 32 f
        int q0 = (bid - 352) * 16;

        wc2s[tid] = Wc2[tid];
        if (tid < 32) confl[tid] = 0.f;
#pragma unroll
        for (int i = 0; i < 8; i++) {                  // hp: 2048 float4 -> bf16 short4
            int idx = i * 256 + tid;
            int r = idx >> 6, c = (idx & 63) * 4;
            float4 v = *(const float4*)&hpb[r * 256 + c];
            short4_t o;
            o[0] = f2bf(v.x); o[1] = f2bf(v.y); o[2] = f2bf(v.z); o[3] = f2bf(v.w);
            *(short4_t*)&hp_s[r * 260 + c] = o;
        }
        {   // hq tile: [16 q][256 h] = qf2b[q0..q0+16] @ wqp, K=512 (bf16 A direct-load)
            floatx4 acc[4];
#pragma unroll
            for (int nt = 0; nt < 4; nt++) acc[nt] = (floatx4){0.f, 0.f, 0.f, 0.f};
            const short* qa = qf2b + (size_t)(q0 + ml) * 512 + q8 * 8;
#pragma unroll 4
            for (int kc = 0; kc < 512; kc += 32) {
                S8B8 a; a.s = *(const short8*)&qa[kc];
#pragma unroll
                for (int nt = 0; nt < 4; nt++) {
                    int col = w * 64 + nt * 16 + ml;
                    S8B8 b; b.s = *(const short8*)&wqp[((size_t)((kc >> 3) + q8) * 256 + col) * 8];
                    acc[nt] = __builtin_amdgcn_mfma_f32_16x16x32_bf16(a.b, b.b, acc[nt], 0, 0, 0);
                }
            }
#pragma unroll
            for (int nt = 0; nt < 4; nt++)
#pragma unroll
                for (int r = 0; r < 4; r++)
                    hq_lds[(q8 * 4 + r) * 280 + w * 64 + nt * 16 + ml] = f2bf(acc[nt][r]);
        }
        __syncthreads();

        int q = tid & 15, kg = tid >> 4;
        int k0 = kg, k1 = kg + 16;
        float s0 = 0.f, s1 = 0.f;
        for (int h = 0; h < 256; h += 4) {
            uint2 hv = *(uint2*)&hq_lds[q * 280 + h];
            float f0 = bflo(hv.x), f1 = bfhi(hv.x), f2 = bflo(hv.y), f3 = bfhi(hv.y);
            uint2 u0 = *(uint2*)&hp_s[k0 * 260 + h];
            uint2 u1 = *(uint2*)&hp_s[k1 * 260 + h];
            float4 wv = *(float4*)&wc2s[h];
            s0 += fmaxf(bflo(u0.x) + f0, 0.f) * wv.x;
            s0 += fmaxf(bfhi(u0.x) + f1, 0.f) * wv.y;
            s0 += fmaxf(bflo(u0.y) + f2, 0.f) * wv.z;
            s0 += fmaxf(bfhi(u0.y) + f3, 0.f) * wv.w;
            s1 += fmaxf(bflo(u1.x) + f0, 0.f) * wv.x;
            s1 += fmaxf(bfhi(u1.x) + f1, 0.f) * wv.y;
            s1 += fmaxf(bflo(u1.y) + f2, 0.f) * wv.z;
            s1 += fmaxf(bfhi(u1.y) + f3, 0.f) * wv.w;
        }
        float bc2 = bc2p[0];
        float v0 = 1.f / (1.f + __expf(-(s0 + bc2)));
        float v1 = 1.f / (1.f + __expf(-(s1 + bc2)));
        atomicAdd(&confl[k0], v0);
        atomicAdd(&confl[k1], v1);
        __syncthreads();
        if (tid < 32) {
            int cell = (tid + bid) & 31;               // de-burst the 1024-way dout contention
            atomicAdd(&dout[16384 + cell], confl[cell] * (1.0f / 16384.0f));
        }
    }
}

// ================ global spin barrier (16 co-resident blocks — PROVEN size, do not widen) ================
__device__ __forceinline__ void gbar(int* bar, int phase, int nblk) {
    __syncthreads();
    if (threadIdx.x == 0) {
        __threadfence();
        __hip_atomic_fetch_add(&bar[phase], 1, __ATOMIC_ACQ_REL, __HIP_MEMORY_SCOPE_AGENT);
        while (__hip_atomic_load(&bar[phase], __ATOMIC_ACQUIRE, __HIP_MEMORY_SCOPE_AGENT) < nblk)
            __builtin_amdgcn_s_sleep(1);
    }
    __syncthreads();
}

// ================ k_D: 16-block fused 3-step MLP (R0 verbatim) ================
__global__ __launch_bounds__(256) void k_D(const float* __restrict__ wmean,
                                           const float* __restrict__ wsuminv,
                                           const short* __restrict__ W1p,
                                           const float* __restrict__ b1,
                                           const short* __restrict__ W2p,
                                           const float* __restrict__ b2,
                                           float* __restrict__ refined,
                                           short* __restrict__ hb,
                                           int* __restrict__ bar,
                                           float* __restrict__ dout) {
    __shared__ float smem[4608];
    int tid = threadIdx.x, lane = tid & 63, w = tid >> 6;
    int ml = lane & 15, q8 = lane >> 4;

    float (*red)[32][36] = (float(*)[32][36])smem;
    int nb = blockIdx.x;
    int phase = 0;
    for (int s = 0; s < 3; s++) {
        {   // layer 1: hb[:, 32-col slice] = relu(concat @ W1 + b1) bf16
            const float* srcA = (w < 2) ? refined : (wmean + (size_t)s * 32 * 512 - 512);
            float iv0 = 1.f, iv1 = 1.f;
            if (w >= 2) {
                iv0 = wsuminv[s * 32 + ml];
                iv1 = wsuminv[s * 32 + 16 + ml];
            }
            int kw = w * 256;
            floatx4 acc[2][2];
#pragma unroll
            for (int mt = 0; mt < 2; mt++)
#pragma unroll
                for (int nt = 0; nt < 2; nt++) acc[mt][nt] = (floatx4){0.f, 0.f, 0.f, 0.f};
            for (int st = 0; st < 8; st++) {
                int k0 = kw + st * 32 + q8 * 8;
                S8B8 a[2];
#pragma unroll
                for (int mt = 0; mt < 2; mt++) {
                    float sc = mt ? iv1 : iv0;
                    const float* p = &srcA[(size_t)(mt * 16 + ml) * 512 + k0];
                    float4 f0 = *(const float4*)p;
                    float4 f1 = *(const float4*)(p + 4);
                    short8 t;
                    t[0] = f2bf(f0.x * sc); t[1] = f2bf(f0.y * sc);
                    t[2] = f2bf(f0.z * sc); t[3] = f2bf(f0.w * sc);
                    t[4] = f2bf(f1.x * sc); t[5] = f2bf(f1.y * sc);
                    t[6] = f2bf(f1.z * sc); t[7] = f2bf(f1.w * sc);
                    a[mt].s = t;
                }
#pragma unroll
                for (int nt = 0; nt < 2; nt++) {
                    int n = nb * 32 + nt * 16 + ml;
                    S8B8 b; b.s = *(const short8*)&W1p[((size_t)(k0 >> 3) * 512 + n) * 8];
#pragma unroll
                    for (int mt = 0; mt < 2; mt++)
                        acc[mt][nt] = __builtin_amdgcn_mfma_f32_16x16x32_bf16(a[mt].b, b.b, acc[mt][nt], 0, 0, 0);
                }
            }
            __syncthreads();
#pragma unroll
            for (int mt = 0; mt < 2; mt++)
#pragma unroll
                for (int nt = 0; nt < 2; nt++)
#pragma unroll
                    for (int r = 0; r < 4; r++)
                        red[w][mt * 16 + q8 * 4 + r][nt * 16 + ml] = acc[mt][nt][r];
            __syncthreads();
            int m = tid >> 3, n0 = (tid & 7) * 4;
            short4_t o;
#pragma unroll
            for (int i = 0; i < 4; i++) {
                float v = b1[nb * 32 + n0 + i];
#pragma unroll
                for (int w4 = 0; w4 < 4; w4++) v += red[w4][m][n0 + i];
                o[i] = f2bf(fmaxf(v, 0.f));
            }
            *(short4_t*)&hb[(size_t)m * 512 + nb * 32 + n0] = o;
        }
        gbar(bar, phase++, 16);
        {   // layer 2: refined[:, slice] += 0.1*(hb @ W2 + b2)
            int kw = w * 128;
            floatx4 acc[2][2];
#pragma unroll
            for (int mt = 0; mt < 2; mt++)
#pragma unroll
                for (int nt = 0; nt < 2; nt++) acc[mt][nt] = (floatx4){0.f, 0.f, 0.f, 0.f};
            for (int st = 0; st < 4; st++) {
                int k0 = kw + st * 32 + q8 * 8;
                S8B8 a[2];
#pragma unroll
                for (int mt = 0; mt < 2; mt++)
                    a[mt].s = *(const short8*)&hb[(size_t)(mt * 16 + ml) * 512 + k0];
#pragma unroll
                for (int nt = 0; nt < 2; nt++) {
                    int n = nb * 32 + nt * 16 + ml;
                    S8B8 b; b.s = *(const short8*)&W2p[((size_t)(k0 >> 3) * 512 + n) * 8];
#pragma unroll
                    for (int mt = 0; mt < 2; mt++)
                        acc[mt][nt] = __builtin_amdgcn_mfma_f32_16x16x32_bf16(a[mt].b, b.b, acc[mt][nt], 0, 0, 0);
                }
            }
            __syncthreads();
#pragma unroll
            for (int mt = 0; mt < 2; mt++)
#pragma unroll
                for (int nt = 0; nt < 2; nt++)
#pragma unroll
                    for (int r = 0; r < 4; r++)
                        red[w][mt * 16 + q8 * 4 + r][nt * 16 + ml] = acc[mt][nt][r];
            __syncthreads();
            int m = tid >> 3, n0 = (tid & 7) * 4;
#pragma unroll
            for (int i = 0; i < 4; i++) {
                int c = nb * 32 + n0 + i;
                float v = b2[c];
#pragma unroll
                for (int w4 = 0; w4 < 4; w4++) v += red[w4][m][n0 + i];
                float val = refined[(size_t)m * 512 + c] + 0.1f * v;
                refined[(size_t)m * 512 + c] = val;
                if (s == 2) dout[(size_t)m * 512 + c] = val;
            }
        }
        if (s < 2) gbar(bar, phase++, 16);
    }
}

extern "C" void kernel_launch(void* const* d_in, const int* in_sizes, int n_in,
                              void* d_out, int out_size, void* d_ws, size_t ws_size,
                              hipStream_t stream) {
    const float* proto = (const float*)d_in[0];
    const float* qf    = (const float*)d_in[1];
    const float* qd    = (const float*)d_in[2];
    const float* W1    = (const float*)d_in[3];
    const float* b1    = (const float*)d_in[4];
    const float* W2    = (const float*)d_in[5];
    const float* b2    = (const float*)d_in[6];
    const float* Wc1   = (const float*)d_in[7];
    const float* bc1   = (const float*)d_in[8];
    const float* Wc2   = (const float*)d_in[9];
    const float* bc2   = (const float*)d_in[10];
    float* out = (float*)d_out;

    float* ws = (float*)d_ws;
    short* softT   = (short*)ws;                 // 1,572,864 s
    short* qf2b    = (short*)(ws + 786432);      // 8,388,608 s
    float* wmean   = ws + 4980736;               // 49,152 f (raw accumulator)
    float* refined = ws + 5029888;               // 16,384 f
    short* hb      = (short*)(ws + 5046272);     // 16,384 s
    short* W1p     = (short*)(ws + 5054464);     // 524,288 s
    short* W2p     = (short*)(ws + 5316608);     // 262,144 s
    short* wqp     = (short*)(ws + 5447680);     // 131,072 s
    float* hpb     = ws + 5513216;               // 8,192 f
    int*   bar     = (int*)(ws + 5521408);       // 8 ints
    float* wsuminv = ws + 5521416;               // 96 f

    k_A<<<2849, 256, 0, stream>>>(qd, W1, W2, Wc1, proto, qf, bc1, softT, W1p, W2p, wqp,
                                  refined, qf2b, wmean, hpb, bar, out);
    k_B<<<1376, 256, 0, stream>>>(qf2b, softT, wmean, wsuminv, wqp, hpb, Wc2, bc2, out);
    k_D<<<16, 256, 0, stream>>>(wmean, wsuminv, W1p, b1, W2p, b2, refined, hb, bar, out);
}

// Round 6
// 181.022 us; speedup vs baseline: 1.3648x; 1.1086x over previous
//
#include <hip/hip_runtime.h>

#define NQg 16384

typedef __attribute__((ext_vector_type(8))) short short8;
typedef __attribute__((ext_vector_type(4))) short short4_t;
typedef __attribute__((ext_vector_type(8))) __bf16 bf16x8;
typedef __attribute__((ext_vector_type(4))) float floatx4;

union S8B8 { short8 s; bf16x8 b; };

__device__ __forceinline__ short f2bf(float f) {
    union { float f; unsigned u; } v; v.f = f;
    unsigned r = v.u + 0x7fffu + ((v.u >> 16) & 1u);   // RNE
    return (short)(r >> 16);
}
__device__ __forceinline__ float bf2f(short s) {
    union { unsigned u; float f; } v; v.u = ((unsigned)(unsigned short)s) << 16;
    return v.f;
}
__device__ __forceinline__ float bflo(unsigned u) { return __uint_as_float(u << 16); }
__device__ __forceinline__ float bfhi(unsigned u) { return __uint_as_float(u & 0xffff0000u); }

// ================ k_A: softmax->softT | coalesced packs | inits | hpb (no qf2b cast) ================
__global__ __launch_bounds__(256) void k_A(const float* __restrict__ qd,
                                           const float* __restrict__ W1, const float* __restrict__ W2,
                                           const float* __restrict__ Wc1, const float* __restrict__ proto,
                                           const float* __restrict__ bc1,
                                           short* __restrict__ softT,
                                           short* __restrict__ W1p, short* __restrict__ W2p,
                                           short* __restrict__ wqp, float* __restrict__ refined,
                                           float* __restrict__ wmean, float* __restrict__ hpb,
                                           int* __restrict__ bar, float* __restrict__ dout) {
    int tid = threadIdx.x, bid = blockIdx.x;
    if (bid < 64) {
        // softmax -> softT (R0 verbatim)
        int q = bid * 256 + tid;
        float d[32];
        const float4* p = (const float4*)(qd + (size_t)q * 32);
#pragma unroll
        for (int j = 0; j < 8; j++) {
            float4 v = p[j];
            d[4 * j] = v.x; d[4 * j + 1] = v.y; d[4 * j + 2] = v.z; d[4 * j + 3] = v.w;
        }
#pragma unroll
        for (int s = 0; s < 3; s++) {
            float inv = -1.0f / (float)(s + 1);
            float e[32];
            float sum = 0.f;
#pragma unroll
            for (int k = 0; k < 32; k++) { e[k] = __expf(d[k] * inv); sum += e[k]; }
            float r = 1.0f / sum;
#pragma unroll
            for (int k = 0; k < 32; k++)
                softT[(size_t)(s * 32 + k) * NQg + q] = f2bf(e[k] * r);
        }
        return;
    }
    if (bid < 512) {
        // coalesced packs (R3-proven): thread = 8 consecutive k for one n
        int idx = (bid - 64) * 256 + tid;   // < 114688
        if (idx < 65536) {                  // W1 pack
            int kg = idx >> 9, n = idx & 511;
            short8 o;
#pragma unroll
            for (int j = 0; j < 8; j++) o[j] = f2bf(W1[(size_t)(kg * 8 + j) * 512 + n]);
            *(short8*)&W1p[((size_t)kg * 512 + n) * 8] = o;
        } else if (idx < 98304) {           // W2 pack
            int j2 = idx - 65536;
            int kg = j2 >> 9, n = j2 & 511;
            short8 o;
#pragma unroll
            for (int j = 0; j < 8; j++) o[j] = f2bf(W2[(size_t)(kg * 8 + j) * 512 + n]);
            *(short8*)&W2p[((size_t)kg * 512 + n) * 8] = o;
        } else {                            // Wc1[512:] pack
            int j3 = idx - 98304;
            int kg = j3 >> 8, n = j3 & 255;
            short8 o;
#pragma unroll
            for (int j = 0; j < 8; j++) o[j] = f2bf(Wc1[(size_t)(512 + kg * 8 + j) * 256 + n]);
            *(short8*)&wqp[((size_t)kg * 256 + n) * 8] = o;
        }
        return;
    }
    if (bid < 576) {
        int idx = (bid - 512) * 256 + tid;  // < 16384
        refined[idx] = proto[idx];
        return;
    }
    if (bid < 768) {
        int idx = (bid - 576) * 256 + tid;  // < 49152
        wmean[idx] = 0.f;
        return;
    }
    if (bid < 800) {
        // hpb: 4 independent accumulators + unroll (proven)
        int r = bid - 768;
        const float* pr = proto + r * 512;
        const float* wc = Wc1 + tid;
        float a0 = 0.f, a1 = 0.f, a2 = 0.f, a3 = 0.f;
#pragma unroll 4
        for (int i = 0; i < 512; i += 4) {
            float4 p4 = *(const float4*)&pr[i];
            float w0 = wc[(size_t)i * 256];
            float w1 = wc[(size_t)(i + 1) * 256];
            float w2 = wc[(size_t)(i + 2) * 256];
            float w3 = wc[(size_t)(i + 3) * 256];
            a0 += p4.x * w0;
            a1 += p4.y * w1;
            a2 += p4.z * w2;
            a3 += p4.w * w3;
        }
        hpb[r * 256 + tid] = bc1[tid] + ((a0 + a1) + (a2 + a3));
        return;
    }
    {
        if (tid < 8) bar[tid] = 0;
        else if (tid >= 32 && tid < 64) dout[16384 + tid - 32] = 0.f;
    }
}

// ================ global spin barrier (16 co-resident blocks — PROVEN size, do not widen) ================
__device__ __forceinline__ void gbar(int* bar, int phase, int nblk) {
    __syncthreads();
    if (threadIdx.x == 0) {
        __threadfence();
        __hip_atomic_fetch_add(&bar[phase], 1, __ATOMIC_ACQ_REL, __HIP_MEMORY_SCOPE_AGENT);
        while (__hip_atomic_load(&bar[phase], __ATOMIC_ACQUIRE, __HIP_MEMORY_SCOPE_AGENT) < nblk)
            __builtin_amdgcn_s_sleep(1);
    }
    __syncthreads();
}

// ======== k_B: 0..15 MLP (spin-waits bar[7]==352) | 16..271 wmean | 272..367 wsum | 368..1391 conf ========
__global__ __launch_bounds__(256) void k_B(const float* __restrict__ qf,
                                           const short* __restrict__ softT,
                                           float* __restrict__ wmean,
                                           float* __restrict__ wsuminv,
                                           const short* __restrict__ wqp,
                                           const float* __restrict__ hpb,
                                           const float* __restrict__ Wc2,
                                           const float* __restrict__ bc2p,
                                           const short* __restrict__ W1p,
                                           const float* __restrict__ b1,
                                           const short* __restrict__ W2p,
                                           const float* __restrict__ b2,
                                           float* __restrict__ refined,
                                           short* __restrict__ hb,
                                           int* __restrict__ bar,
                                           float* __restrict__ dout) {
    __shared__ float smem[6688];   // 26,752 B for all branches
    int tid = threadIdx.x;
    int lane = tid & 63, w = tid >> 6;
    int ml = lane & 15, q8 = lane >> 4;
    int bid = blockIdx.x;

    if (bid < 16) {
        // ---- MLP: wait for wmean (256) + wsum (96) producers, then R0-verbatim 3-step loop ----
        if (tid == 0) {
            while (__hip_atomic_load(&bar[7], __ATOMIC_ACQUIRE, __HIP_MEMORY_SCOPE_AGENT) < 352)
                __builtin_amdgcn_s_sleep(1);
        }
        __syncthreads();
        float (*red)[32][36] = (float(*)[32][36])smem;   // 4608 f
        int nb = bid;
        int phase = 0;
        for (int s = 0; s < 3; s++) {
            {   // layer 1: hb[:, 32-col slice] = relu(concat @ W1 + b1) bf16
                const float* srcA = (w < 2) ? refined : (wmean + (size_t)s * 32 * 512 - 512);
                float iv0 = 1.f, iv1 = 1.f;
                if (w >= 2) {
                    iv0 = wsuminv[s * 32 + ml];
                    iv1 = wsuminv[s * 32 + 16 + ml];
                }
                int kw = w * 256;
                floatx4 acc[2][2];
#pragma unroll
                for (int mt = 0; mt < 2; mt++)
#pragma unroll
                    for (int nt = 0; nt < 2; nt++) acc[mt][nt] = (floatx4){0.f, 0.f, 0.f, 0.f};
                for (int st = 0; st < 8; st++) {
                    int k0 = kw + st * 32 + q8 * 8;
                    S8B8 a[2];
#pragma unroll
                    for (int mt = 0; mt < 2; mt++) {
                        float sc = mt ? iv1 : iv0;
                        const float* p = &srcA[(size_t)(mt * 16 + ml) * 512 + k0];
                        float4 f0 = *(const float4*)p;
                        float4 f1 = *(const float4*)(p + 4);
                        short8 t;
                        t[0] = f2bf(f0.x * sc); t[1] = f2bf(f0.y * sc);
                        t[2] = f2bf(f0.z * sc); t[3] = f2bf(f0.w * sc);
                        t[4] = f2bf(f1.x * sc); t[5] = f2bf(f1.y * sc);
                        t[6] = f2bf(f1.z * sc); t[7] = f2bf(f1.w * sc);
                        a[mt].s = t;
                    }
#pragma unroll
                    for (int nt = 0; nt < 2; nt++) {
                        int n = nb * 32 + nt * 16 + ml;
                        S8B8 b; b.s = *(const short8*)&W1p[((size_t)(k0 >> 3) * 512 + n) * 8];
#pragma unroll
                        for (int mt = 0; mt < 2; mt++)
                            acc[mt][nt] = __builtin_amdgcn_mfma_f32_16x16x32_bf16(a[mt].b, b.b, acc[mt][nt], 0, 0, 0);
                    }
                }
                __syncthreads();
#pragma unroll
                for (int mt = 0; mt < 2; mt++)
#pragma unroll
                    for (int nt = 0; nt < 2; nt++)
#pragma unroll
                        for (int r = 0; r < 4; r++)
                            red[w][mt * 16 + q8 * 4 + r][nt * 16 + ml] = acc[mt][nt][r];
                __syncthreads();
                int m = tid >> 3, n0 = (tid & 7) * 4;
                short4_t o;
#pragma unroll
                for (int i = 0; i < 4; i++) {
                    float v = b1[nb * 32 + n0 + i];
#pragma unroll
                    for (int w4 = 0; w4 < 4; w4++) v += red[w4][m][n0 + i];
                    o[i] = f2bf(fmaxf(v, 0.f));
                }
                *(short4_t*)&hb[(size_t)m * 512 + nb * 32 + n0] = o;
            }
            gbar(bar, phase++, 16);
            {   // layer 2: refined[:, slice] += 0.1*(hb @ W2 + b2)
                int kw = w * 128;
                floatx4 acc[2][2];
#pragma unroll
                for (int mt = 0; mt < 2; mt++)
#pragma unroll
                    for (int nt = 0; nt < 2; nt++) acc[mt][nt] = (floatx4){0.f, 0.f, 0.f, 0.f};
                for (int st = 0; st < 4; st++) {
                    int k0 = kw + st * 32 + q8 * 8;
                    S8B8 a[2];
#pragma unroll
                    for (int mt = 0; mt < 2; mt++)
                        a[mt].s = *(const short8*)&hb[(size_t)(mt * 16 + ml) * 512 + k0];
#pragma unroll
                    for (int nt = 0; nt < 2; nt++) {
                        int n = nb * 32 + nt * 16 + ml;
                        S8B8 b; b.s = *(const short8*)&W2p[((size_t)(k0 >> 3) * 512 + n) * 8];
#pragma unroll
                        for (int mt = 0; mt < 2; mt++)
                            acc[mt][nt] = __builtin_amdgcn_mfma_f32_16x16x32_bf16(a[mt].b, b.b, acc[mt][nt], 0, 0, 0);
                    }
                }
                __syncthreads();
#pragma unroll
                for (int mt = 0; mt < 2; mt++)
#pragma unroll
                    for (int nt = 0; nt < 2; nt++)
#pragma unroll
                        for (int r = 0; r < 4; r++)
                            red[w][mt * 16 + q8 * 4 + r][nt * 16 + ml] = acc[mt][nt][r];
                __syncthreads();
                int m = tid >> 3, n0 = (tid & 7) * 4;
#pragma unroll
                for (int i = 0; i < 4; i++) {
                    int c = nb * 32 + n0 + i;
                    float v = b2[c];
#pragma unroll
                    for (int w4 = 0; w4 < 4; w4++) v += red[w4][m][n0 + i];
                    float val = refined[(size_t)m * 512 + c] + 0.1f * v;
                    refined[(size_t)m * 512 + c] = val;
                    if (s == 2) dout[(size_t)m * 512 + c] = val;
                }
            }
            if (s < 2) gbar(bar, phase++, 16);
        }
        return;
    }

    if (bid < 272) {
        // ---- wmean producer (R0-verbatim structure; B from fp32 qf inline-cast (R3-proven); R0 atomic order) ----
        short* B_lds = (short*)smem;       // [128][40]
        int kc = (bid - 16) >> 2, ns = (bid - 16) & 3;
        int c0 = ns * 128;
        int qbase0 = kc * 256;
        int c_l = 2 * lane;
        int q_l = 8 * w;

        floatx4 acc[6][2];
#pragma unroll
        for (int mt = 0; mt < 6; mt++)
#pragma unroll
            for (int nt = 0; nt < 2; nt++) acc[mt][nt] = (floatx4){0.f, 0.f, 0.f, 0.f};

        for (int step = 0; step < 8; step++) {
            int qb = qbase0 + step * 32;
            short8 sA, sB;
#pragma unroll
            for (int i = 0; i < 8; i++) {
                float2 u = *(const float2*)&qf[(size_t)(qb + q_l + i) * 512 + c0 + c_l];
                sA[i] = f2bf(u.x);
                sB[i] = f2bf(u.y);
            }
            __syncthreads();
            *(short8*)&B_lds[c_l * 40 + q_l] = sA;
            *(short8*)&B_lds[(c_l + 1) * 40 + q_l] = sB;
            S8B8 a[6];
#pragma unroll
            for (int mt = 0; mt < 6; mt++)
                a[mt].s = *(const short8*)&softT[(size_t)(mt * 16 + ml) * NQg + qb + q8 * 8];
            __syncthreads();
#pragma unroll
            for (int nt = 0; nt < 2; nt++) {
                S8B8 b; b.s = *(short8*)&B_lds[(w * 32 + nt * 16 + ml) * 40 + q8 * 8];
#pragma unroll
                for (int mt = 0; mt < 6; mt++)
                    acc[mt][nt] = __builtin_amdgcn_mfma_f32_16x16x32_bf16(a[mt].b, b.b, acc[mt][nt], 0, 0, 0);
            }
        }
#pragma unroll
        for (int mt = 0; mt < 6; mt++) {
#pragma unroll
            for (int nt = 0; nt < 2; nt++) {
                int c = c0 + w * 32 + nt * 16 + ml;
#pragma unroll
                for (int r = 0; r < 4; r++) {
                    int m = mt * 16 + q8 * 4 + r;
                    atomicAdd(&wmean[(size_t)m * 512 + c], acc[mt][nt][r]);
                }
            }
        }
        __syncthreads();
        if (tid == 0) {
            __threadfence();
            __hip_atomic_fetch_add(&bar[7], 1, __ATOMIC_ACQ_REL, __HIP_MEMORY_SCOPE_AGENT);
        }
        return;
    }

    if (bid < 368) {
        // ---- wsuminv (R0 verbatim) + signal ----
        float* red = smem;
        int sk = bid - 272;
        const short* row = softT + (size_t)sk * NQg;
        float s = 0.f;
#pragma unroll
        for (int j = 0; j < 8; j++) {
            short8 v = *(const short8*)&row[j * 2048 + tid * 8];
#pragma unroll
            for (int i = 0; i < 8; i++) s += bf2f(v[i]);
        }
        red[tid] = s;
        __syncthreads();
        for (int off = 128; off > 0; off >>= 1) {
            if (tid < off) red[tid] += red[tid + off];
            __syncthreads();
        }
        if (tid == 0) {
            wsuminv[sk] = 1.0f / fmaxf(red[0], 1e-6f);
            __threadfence();
            __hip_atomic_fetch_add(&bar[7], 1, __ATOMIC_ACQ_REL, __HIP_MEMORY_SCOPE_AGENT);
        }
        return;
    }

    {
        // ---- confidence (R3-verbatim): in-block hq from fp32 qf ----
        short* hq_lds = (short*)smem;                  // [16][280] s
        short* hp_s   = (short*)smem + 4480;           // [32][260] s
        float* wc2s   = smem + 6400;                   // 256 f
        float* confl  = smem + 6656;                   // 32 f
        int q0 = (bid - 368) * 16;

        wc2s[tid] = Wc2[tid];
        if (tid < 32) confl[tid] = 0.f;
#pragma unroll
        for (int i = 0; i < 8; i++) {                  // hp: 2048 float4 -> bf16 short4
            int idx = i * 256 + tid;
            int r = idx >> 6, c = (idx & 63) * 4;
            float4 v = *(const float4*)&hpb[r * 256 + c];
            short4_t o;
            o[0] = f2bf(v.x); o[1] = f2bf(v.y); o[2] = f2bf(v.z); o[3] = f2bf(v.w);
            *(short4_t*)&hp_s[r * 260 + c] = o;
        }
        {   // hq tile: [16 q][256 h] = qf[q0..q0+16] @ wqp, K=512
            floatx4 acc[4];
#pragma unroll
            for (int nt = 0; nt < 4; nt++) acc[nt] = (floatx4){0.f, 0.f, 0.f, 0.f};
            const float* qfa = qf + (size_t)(q0 + ml) * 512 + q8 * 8;
#pragma unroll 4
            for (int kc = 0; kc < 512; kc += 32) {
                float4 fa = *(const float4*)&qfa[kc];
                float4 fb = *(const float4*)&qfa[kc + 4];
                short8 t;
                t[0] = f2bf(fa.x); t[1] = f2bf(fa.y); t[2] = f2bf(fa.z); t[3] = f2bf(fa.w);
                t[4] = f2bf(fb.x); t[5] = f2bf(fb.y); t[6] = f2bf(fb.z); t[7] = f2bf(fb.w);
                S8B8 a; a.s = t;
#pragma unroll
                for (int nt = 0; nt < 4; nt++) {
                    int col = w * 64 + nt * 16 + ml;
                    S8B8 b; b.s = *(const short8*)&wqp[((size_t)((kc >> 3) + q8) * 256 + col) * 8];
                    acc[nt] = __builtin_amdgcn_mfma_f32_16x16x32_bf16(a.b, b.b, acc[nt], 0, 0, 0);
                }
            }
#pragma unroll
            for (int nt = 0; nt < 4; nt++)
#pragma unroll
                for (int r = 0; r < 4; r++)
                    hq_lds[(q8 * 4 + r) * 280 + w * 64 + nt * 16 + ml] = f2bf(acc[nt][r]);
        }
        __syncthreads();

        int q = tid & 15, kg = tid >> 4;
        int k0 = kg, k1 = kg + 16;
        float s0 = 0.f, s1 = 0.f;
        for (int h = 0; h < 256; h += 4) {
            uint2 hv = *(uint2*)&hq_lds[q * 280 + h];
            float f0 = bflo(hv.x), f1 = bfhi(hv.x), f2 = bflo(hv.y), f3 = bfhi(hv.y);
            uint2 u0 = *(uint2*)&hp_s[k0 * 260 + h];
            uint2 u1 = *(uint2*)&hp_s[k1 * 260 + h];
            float4 wv = *(float4*)&wc2s[h];
            s0 += fmaxf(bflo(u0.x) + f0, 0.f) * wv.x;
            s0 += fmaxf(bfhi(u0.x) + f1, 0.f) * wv.y;
            s0 += fmaxf(bflo(u0.y) + f2, 0.f) * wv.z;
            s0 += fmaxf(bfhi(u0.y) + f3, 0.f) * wv.w;
            s1 += fmaxf(bflo(u1.x) + f0, 0.f) * wv.x;
            s1 += fmaxf(bfhi(u1.x) + f1, 0.f) * wv.y;
            s1 += fmaxf(bflo(u1.y) + f2, 0.f) * wv.z;
            s1 += fmaxf(bfhi(u1.y) + f3, 0.f) * wv.w;
        }
        float bc2 = bc2p[0];
        float v0 = 1.f / (1.f + __expf(-(s0 + bc2)));
        float v1 = 1.f / (1.f + __expf(-(s1 + bc2)));
        atomicAdd(&confl[k0], v0);
        atomicAdd(&confl[k1], v1);
        __syncthreads();
        if (tid < 32) {
            int cell = (tid + bid) & 31;               // de-burst the 1024-way dout contention
            atomicAdd(&dout[16384 + cell], confl[cell] * (1.0f / 16384.0f));
        }
    }
}

extern "C" void kernel_launch(void* const* d_in, const int* in_sizes, int n_in,
                              void* d_out, int out_size, void* d_ws, size_t ws_size,
                              hipStream_t stream) {
    const float* proto = (const float*)d_in[0];
    const float* qf    = (const float*)d_in[1];
    const float* qd    = (const float*)d_in[2];
    const float* W1    = (const float*)d_in[3];
    const float* b1    = (const float*)d_in[4];
    const float* W2    = (const float*)d_in[5];
    const float* b2    = (const float*)d_in[6];
    const float* Wc1   = (const float*)d_in[7];
    const float* bc1   = (const float*)d_in[8];
    const float* Wc2   = (const float*)d_in[9];
    const float* bc2   = (const float*)d_in[10];
    float* out = (float*)d_out;

    float* ws = (float*)d_ws;
    short* softT   = (short*)ws;                 // 1,572,864 s
    float* wmean   = ws + 786432;                // 49,152 f (raw accumulator)
    float* refined = ws + 835584;                // 16,384 f
    short* hb      = (short*)(ws + 851968);      // 16,384 s
    short* W1p     = (short*)(ws + 860160);      // 524,288 s
    short* W2p     = (short*)(ws + 1122304);     // 262,144 s
    short* wqp     = (short*)(ws + 1253376);     // 131,072 s
    float* hpb     = ws + 1318912;               // 8,192 f
    int*   bar     = (int*)(ws + 1327104);       // 8 ints
    float* wsuminv = ws + 1327112;               // 96 f

    k_A<<<801, 256, 0, stream>>>(qd, W1, W2, Wc1, proto, bc1, softT, W1p, W2p, wqp,
                                 refined, wmean, hpb, bar, out);
    k_B<<<1392, 256, 0, stream>>>(qf, softT, wmean, wsuminv, wqp, hpb, Wc2, bc2,
                                  W1p, b1, W2p, b2, refined, hb, bar, out);
}